// Round 4
// baseline (387.547 us; speedup 1.0000x reference)
//
#include <hip/hip_runtime.h>
#include <hip/hip_bf16.h>
#include <math.h>

constexpr int S_LEN = 2048;
constexpr int B_SZ  = 4;
constexpr int NROWS = B_SZ * S_LEN;   // 8192
constexpr float GAIN_  = 0.25f;
constexpr float EPS_   = 1e-6f;
constexpr float THETA_ = 10000.0f;
constexpr float LOG2E_ = 1.44269504f;

typedef __attribute__((ext_vector_type(8))) short short8;
typedef __attribute__((ext_vector_type(4))) short sshort4;
typedef __attribute__((ext_vector_type(4))) float float4v;

__device__ __forceinline__ short f2bs(float f) {
    __hip_bfloat16 h = __float2bfloat16(f);
    short r;
    __builtin_memcpy(&r, &h, 2);
    return r;
}

__device__ __forceinline__ void async_copy16(const short* g, short* l) {
    __builtin_amdgcn_global_load_lds(
        (const __attribute__((address_space(1))) void*)g,
        (__attribute__((address_space(3))) void*)l, 16, 0, 0);
}

// bijective XCD-chunked remap (T1); requires nwg % 8 == 0
__device__ __forceinline__ int xcd_remap(int nwg) {
    int orig = blockIdx.x + gridDim.x * (blockIdx.y + gridDim.y * blockIdx.z);
    return (orig & 7) * (nwg >> 3) + (orig >> 3);
}

__device__ __forceinline__ float block_reduce_sum_256(float v, float* scratch) {
    __syncthreads();
    for (int off = 32; off > 0; off >>= 1)
        v += __shfl_down(v, off, 64);
    int lane = threadIdx.x & 63;
    int wid  = threadIdx.x >> 6;
    if (lane == 0) scratch[wid] = v;
    __syncthreads();
    return scratch[0] + scratch[1] + scratch[2] + scratch[3];
}

// two sums in one shuffle pass: 2 barriers instead of 6
__device__ __forceinline__ void block_reduce_sum2_256(float& a, float& b, float* scratch) {
    __syncthreads();
    for (int off = 32; off > 0; off >>= 1) {
        a += __shfl_down(a, off, 64);
        b += __shfl_down(b, off, 64);
    }
    int lane = threadIdx.x & 63;
    int wid  = threadIdx.x >> 6;
    if (lane == 0) { scratch[wid] = a; scratch[4 + wid] = b; }
    __syncthreads();
    a = scratch[0] + scratch[1] + scratch[2] + scratch[3];
    b = scratch[4] + scratch[5] + scratch[6] + scratch[7];
}

// three sums in one shuffle pass: 2 barriers instead of 9
__device__ __forceinline__ void block_reduce_sum3_256(float& a, float& b, float& c, float* scratch) {
    __syncthreads();
    for (int off = 32; off > 0; off >>= 1) {
        a += __shfl_down(a, off, 64);
        b += __shfl_down(b, off, 64);
        c += __shfl_down(c, off, 64);
    }
    int lane = threadIdx.x & 63;
    int wid  = threadIdx.x >> 6;
    if (lane == 0) { scratch[wid] = a; scratch[4 + wid] = b; scratch[8 + wid] = c; }
    __syncthreads();
    a = scratch[0] + scratch[1] + scratch[2] + scratch[3];
    b = scratch[4] + scratch[5] + scratch[6] + scratch[7];
    c = scratch[8] + scratch[9] + scratch[10] + scratch[11];
}

// fp32 -> bf16 cast, n % 4 == 0
__global__ __launch_bounds__(256) void cvt_bf16(
    const float* __restrict__ src, short* __restrict__ dst, int n) {
    int i = (blockIdx.x * 256 + threadIdx.x) * 4;
    if (i >= n) return;
    float4 v = *(const float4*)(src + i);
    sshort4 o;
    o.x = f2bs(v.x); o.y = f2bs(v.y); o.z = f2bs(v.z); o.w = f2bs(v.w);
    *(sshort4*)(dst + i) = o;
}

// all four weight casts in one launch: wq|wk|wv -> wqkvb (concat), wo -> wob
__global__ __launch_bounds__(256) void cvt_weights(
    const float* __restrict__ wq, const float* __restrict__ wk,
    const float* __restrict__ wv, const float* __restrict__ wo,
    short* __restrict__ wqkvb, short* __restrict__ wob) {
    int i = (blockIdx.x * 256 + threadIdx.x) * 4;
    const float* src;
    short* dst;
    int j;
    if (i < 1048576)      { src = wq; dst = wqkvb + i; j = i; }
    else if (i < 1310720) { src = wk; dst = wqkvb + i; j = i - 1048576; }
    else if (i < 1572864) { src = wv; dst = wqkvb + i; j = i - 1310720; }
    else                  { src = wo; dst = wob + (i - 1572864); j = i - 1572864; }
    float4 v = *(const float4*)(src + j);
    sshort4 o;
    o.x = f2bs(v.x); o.y = f2bs(v.y); o.z = f2bs(v.z); o.w = f2bs(v.w);
    *(sshort4*)dst = o;
}

// C[M x N] fp32 = A[M x K](bf16) @ B[N x K](bf16)^T.  M%128==0, N%128==0, K%32==0.
// XCD-chunked block swizzle for L2 panel reuse.
__global__ __launch_bounds__(256) void gemm_bf16_mfma(
    const short* __restrict__ A, const short* __restrict__ B,
    float* __restrict__ C, int N, int K) {
    __shared__ short As[128 * 32];
    __shared__ short Bs[128 * 32];
    int tid = threadIdx.x;
    int wave = tid >> 6, lane = tid & 63;
    int wg = xcd_remap(gridDim.x * gridDim.y);
    int bx = wg % gridDim.x, by = wg / gridDim.x;
    int m0 = by * 128, n0 = bx * 128;
    int wm = (wave >> 1) * 64, wn = (wave & 1) * 64;
    int mrow = lane & 15, quad = lane >> 4;
    float4v acc[4][4] = {};
    for (int k0 = 0; k0 < K; k0 += 32) {
        __syncthreads();
#pragma unroll
        for (int p = 0; p < 2; ++p) {
            int f = p * 256 + tid;
            int row = f >> 2, ch = (f & 3) * 8;
            const short* ga = A + (size_t)(m0 + row) * K + k0 + ch;
            const short* gb = B + (size_t)(n0 + row) * K + k0 + ch;
            async_copy16(ga, As + p * 2048 + wave * 512);
            async_copy16(gb, Bs + p * 2048 + wave * 512);
        }
        __syncthreads();
        short8 af[4], bf[4];
#pragma unroll
        for (int i = 0; i < 4; ++i)
            af[i] = *(const short8*)&As[(wm + i * 16 + mrow) * 32 + quad * 8];
#pragma unroll
        for (int j = 0; j < 4; ++j)
            bf[j] = *(const short8*)&Bs[(wn + j * 16 + mrow) * 32 + quad * 8];
#pragma unroll
        for (int i = 0; i < 4; ++i)
#pragma unroll
            for (int j = 0; j < 4; ++j)
                acc[i][j] = __builtin_amdgcn_mfma_f32_16x16x32_bf16(af[i], bf[j], acc[i][j], 0, 0, 0);
    }
#pragma unroll
    for (int i = 0; i < 4; ++i)
#pragma unroll
        for (int r = 0; r < 4; ++r) {
            int m = m0 + wm + i * 16 + quad * 4 + r;
            float* crow = C + (size_t)m * N + n0 + wn;
#pragma unroll
            for (int j = 0; j < 4; ++j)
                crow[j * 16 + mrow] = acc[i][j][r];
        }
}

// split-K x2 variant: z selects K-half; z=0 -> C0, z=1 -> C1 (summed later).
// XCD-chunked swizzle over the full 768-block grid.
__global__ __launch_bounds__(256) void gemm_bf16_mfma_sk2(
    const short* __restrict__ A, const short* __restrict__ B,
    float* __restrict__ C0, float* __restrict__ C1, int N, int K) {
    __shared__ short As[128 * 32];
    __shared__ short Bs[128 * 32];
    int tid = threadIdx.x;
    int wave = tid >> 6, lane = tid & 63;
    int wg = xcd_remap(gridDim.x * gridDim.y * gridDim.z);
    int bx = wg % gridDim.x;
    int t  = wg / gridDim.x;
    int by = t % gridDim.y;
    int bz = t / gridDim.y;
    int m0 = by * 128, n0 = bx * 128;
    int wm = (wave >> 1) * 64, wn = (wave & 1) * 64;
    int mrow = lane & 15, quad = lane >> 4;
    int kh = K >> 1;
    int kbeg = bz * kh, kend = kbeg + kh;
    float* __restrict__ C = bz ? C1 : C0;
    float4v acc[4][4] = {};
    for (int k0 = kbeg; k0 < kend; k0 += 32) {
        __syncthreads();
#pragma unroll
        for (int p = 0; p < 2; ++p) {
            int f = p * 256 + tid;
            int row = f >> 2, ch = (f & 3) * 8;
            const short* ga = A + (size_t)(m0 + row) * K + k0 + ch;
            const short* gb = B + (size_t)(n0 + row) * K + k0 + ch;
            async_copy16(ga, As + p * 2048 + wave * 512);
            async_copy16(gb, Bs + p * 2048 + wave * 512);
        }
        __syncthreads();
        short8 af[4], bf[4];
#pragma unroll
        for (int i = 0; i < 4; ++i)
            af[i] = *(const short8*)&As[(wm + i * 16 + mrow) * 32 + quad * 8];
#pragma unroll
        for (int j = 0; j < 4; ++j)
            bf[j] = *(const short8*)&Bs[(wn + j * 16 + mrow) * 32 + quad * 8];
#pragma unroll
        for (int i = 0; i < 4; ++i)
#pragma unroll
            for (int j = 0; j < 4; ++j)
                acc[i][j] = __builtin_amdgcn_mfma_f32_16x16x32_bf16(af[i], bf[j], acc[i][j], 0, 0, 0);
    }
#pragma unroll
    for (int i = 0; i < 4; ++i)
#pragma unroll
        for (int r = 0; r < 4; ++r) {
            int m = m0 + wm + i * 16 + quad * 4 + r;
            float* crow = C + (size_t)m * N + n0 + wn;
#pragma unroll
            for (int j = 0; j < 4; ++j)
                crow[j * 16 + mrow] = acc[i][j][r];
        }
}

// RMS of q (512, g_latent), k (128, g_kv), v (128, g_kv); sums the two split-K
// partials first. q,k stored back to qkv, v stored as bf16 transposed
// vtb[(b*4+kvh)*32+d][s]. Also head-means of q and k.
__global__ __launch_bounds__(256) void rms_qkv_means(
    float* __restrict__ qkv, const float* __restrict__ qkv2,
    const float* __restrict__ g_latent, const float* __restrict__ g_kv,
    float* __restrict__ qmean, float* __restrict__ kmean,
    short* __restrict__ vtb) {
    int row = blockIdx.x;
    int b = row >> 11, s = row & (S_LEN - 1);
    float* p = qkv + (size_t)row * 768;
    const float* p2 = qkv2 + (size_t)row * 768;
    __shared__ float sh[640];
    __shared__ float scratch[12];
    int tid = threadIdx.x;
    float v0 = p[tid] + p2[tid];
    float v1 = p[tid + 256] + p2[tid + 256];
    float v2 = p[tid + 512] + p2[tid + 512];
    float sq = v0 * v0 + v1 * v1;
    float sk = (tid < 128) ? v2 * v2 : 0.f;
    float sv = (tid >= 128) ? v2 * v2 : 0.f;
    block_reduce_sum3_256(sq, sk, sv, scratch);
    float rq = rsqrtf(sq / 512.f + EPS_);
    float q0 = v0 * rq * g_latent[tid];
    float q1 = v1 * rq * g_latent[tid + 256];
    p[tid] = q0; p[tid + 256] = q1;
    sh[tid] = q0; sh[tid + 256] = q1;
    if (tid < 128) {
        float rk = rsqrtf(sk / 128.f + EPS_);
        float kv = v2 * rk * g_kv[tid];
        p[512 + tid] = kv; sh[512 + tid] = kv;
    } else {
        float rv = rsqrtf(sv / 128.f + EPS_);
        float vv = v2 * rv * g_kv[tid - 128];
        int d_full = tid - 128;
        vtb[((size_t)(b * 4 + (d_full >> 5)) * 32 + (d_full & 31)) * S_LEN + s] = f2bs(vv);
    }
    __syncthreads();
    if (tid < 32) {
        float sm = 0.f;
#pragma unroll
        for (int h = 0; h < 16; ++h) sm += sh[h * 32 + tid];
        qmean[(size_t)row * 32 + tid] = sm * (1.f / 16.f);
    } else if (tid < 64) {
        int d = tid - 32;
        float sm = 0.f;
#pragma unroll
        for (int h = 0; h < 4; ++h) sm += sh[512 + h * 32 + d];
        kmean[(size_t)row * 32 + d] = sm * 0.25f;
    }
}

// Grouped causal conv, 32 in / 32 out channels per group, K=3, left pad 2.
__global__ __launch_bounds__(256) void causal_conv32(
    const float* __restrict__ in, int ldin, int inoff,
    const float* __restrict__ w, float* __restrict__ out, int C) {
    int b = blockIdx.z, g = blockIdx.y, s0 = blockIdx.x * 32;
    __shared__ float wsh[32][3][32];   // [ic][tap][oc]
    __shared__ float ish[34][33];      // [pos][ic]
    int tid = threadIdx.x;
    for (int i = tid; i < 32 * 96; i += 256) {
        int oc = i / 96, r = i % 96;
        wsh[r / 3][r % 3][oc] = w[(size_t)(g * 32 + oc) * 96 + r];
    }
    for (int i = tid; i < 34 * 32; i += 256) {
        int pp = i >> 5, ic = i & 31;
        int s = s0 - 2 + pp;
        ish[pp][ic] = (s >= 0) ? in[((size_t)b * S_LEN + s) * ldin + inoff + g * 32 + ic] : 0.f;
    }
    __syncthreads();
    int sl = tid >> 3, oc0 = (tid & 7) * 4;
    float acc[4] = {0.f, 0.f, 0.f, 0.f};
    for (int ic = 0; ic < 32; ++ic) {
        float x0 = ish[sl][ic], x1 = ish[sl + 1][ic], x2 = ish[sl + 2][ic];
#pragma unroll
        for (int j = 0; j < 4; ++j)
            acc[j] += x0 * wsh[ic][0][oc0 + j] + x1 * wsh[ic][1][oc0 + j] + x2 * wsh[ic][2][oc0 + j];
    }
    float* orow = out + ((size_t)b * S_LEN + s0 + sl) * C + g * 32 + oc0;
    orow[0] = acc[0]; orow[1] = acc[1]; orow[2] = acc[2]; orow[3] = acc[3];
}

// Per-row: conv-RMS, + GAIN*mean-mix, post-RMS, per-head L2 norm, RoPE.
// Writes final q (512, pre-scaled by attention scale AND log2(e)) and k (128) as bf16.
__global__ __launch_bounds__(256) void mix_rows(
    const float* __restrict__ convq, const float* __restrict__ convk,
    const float* __restrict__ qmean, const float* __restrict__ kmean,
    const float* __restrict__ g_conv, const float* __restrict__ g_kconv,
    const float* __restrict__ g_postq, const float* __restrict__ g_postk,
    const float* __restrict__ key_temp,
    short* __restrict__ qb, short* __restrict__ kb) {
    int row = blockIdx.x;
    int s = row & (S_LEN - 1);
    int tid = threadIdx.x;
    __shared__ float sh[640];
    __shared__ float scratch[8];
    __shared__ float hscale[20];
    float q0 = convq[(size_t)row * 512 + tid];
    float q1 = convq[(size_t)row * 512 + tid + 256];
    float k0 = (tid < 128) ? convk[(size_t)row * 128 + tid] : 0.f;
    float ssq = q0 * q0 + q1 * q1;
    float ssk = k0 * k0;
    block_reduce_sum2_256(ssq, ssk, scratch);
    float r1  = rsqrtf(ssq / 512.f + EPS_);
    float rk1 = rsqrtf(ssk / 128.f + EPS_);
    float km = kmean[(size_t)row * 32 + (tid & 31)];
    float a0 = q0 * r1 * g_conv[tid] + GAIN_ * km;
    float a1 = q1 * r1 * g_conv[tid + 256] + GAIN_ * km;
    float ak = 0.f;
    if (tid < 128) ak = k0 * rk1 * g_kconv[tid] + GAIN_ * qmean[(size_t)row * 32 + (tid & 31)];
    float ssq2 = a0 * a0 + a1 * a1;
    float ssk2 = ak * ak;
    block_reduce_sum2_256(ssq2, ssk2, scratch);
    float r2  = rsqrtf(ssq2 / 512.f + EPS_);
    float rk2 = rsqrtf(ssk2 / 128.f + EPS_);
    sh[tid] = a0 * r2 * g_postq[tid];
    sh[tid + 256] = a1 * r2 * g_postq[tid + 256];
    if (tid < 128) sh[512 + tid] = ak * rk2 * g_postk[tid];
    __syncthreads();
    if (tid < 16) {
        float ssh = 0.f;
        for (int d = 0; d < 32; ++d) { float x = sh[tid * 32 + d]; ssh += x * x; }
        // sqrt(32)*(1/sqrt(32)) == 1: attention scale folded into q.
        // LOG2E folded too so attn softmax is a bare exp2(st + shift).
        hscale[tid] = LOG2E_ / fmaxf(sqrtf(ssh), 1e-12f);
    } else if (tid < 20) {
        int h = tid - 16;
        float ssh = 0.f;
        for (int d = 0; d < 32; ++d) { float x = sh[512 + h * 32 + d]; ssh += x * x; }
        hscale[tid] = sqrtf(32.f) / fmaxf(sqrtf(ssh), 1e-12f) * key_temp[0];
    }
    __syncthreads();
    {   // q RoPE: 256 pairs, packed 4B store
        int i0 = tid * 2;
        int h = i0 >> 5;
        int fi = (i0 & 31) >> 1;
        float sc = hscale[h];
        float x1 = sh[i0] * sc, x2 = sh[i0 + 1] * sc;
        float freq = powf(THETA_, -(float)fi / 16.f);
        float ang = (float)s * freq;
        float sn, cs;
        sincosf(ang, &sn, &cs);
        unsigned lo = (unsigned short)f2bs(x1 * cs - x2 * sn);
        unsigned hi = (unsigned short)f2bs(x1 * sn + x2 * cs);
        *(unsigned*)(qb + (size_t)row * 512 + i0) = lo | (hi << 16);
    }
    if (tid < 64) {  // k RoPE: 64 pairs, packed 4B store
        int i0 = tid * 2;
        int h = i0 >> 5;
        int fi = (i0 & 31) >> 1;
        float sc = hscale[16 + h];
        float x1 = sh[512 + i0] * sc, x2 = sh[512 + i0 + 1] * sc;
        float freq = powf(THETA_, -(float)fi / 16.f);
        float ang = (float)s * freq;
        float sn, cs;
        sincosf(ang, &sn, &cs);
        unsigned lo = (unsigned short)f2bs(x1 * cs - x2 * sn);
        unsigned hi = (unsigned short)f2bs(x1 * sn + x2 * cs);
        *(unsigned*)(kb + (size_t)row * 128 + i0) = lo | (hi << 16);
    }
}

// MFMA flash attention: qt-paired (balanced) AND k-parity split (2x parallelism).
// VALU-lean softmax: shift folded into MFMA C-init (zinit), LOG2E folded into q,
// bf16 pack via v_cvt_pk_bf16_f32, row-sum l via MFMA against a ones fragment.
// PF stride 76 shorts (152B): pfrag b64-pair reads land 2-way/bank (free) vs the
// old 72-stride 8-way pattern that produced 3.24M SQ_LDS_BANK_CONFLICT.
__global__ __launch_bounds__(256) void attn_mfma(
    const short* __restrict__ qb, const short* __restrict__ kb,
    const short* __restrict__ vtb, float* __restrict__ OnumA,
    float* __restrict__ OnumB, float* __restrict__ LsumA,
    float* __restrict__ LsumB, const float* __restrict__ key_temp) {
    int pp = blockIdx.x, h = blockIdx.y, b = blockIdx.z;
    int pair = pp >> 1, parity = pp & 1;
    int kvh = h >> 2;
    float* __restrict__ Onum = parity ? OnumB : OnumA;
    float* __restrict__ Lsum = parity ? LsumB : LsumA;
    __shared__ short KF[2][2048];                   // K A-frags, dbuf 8KB
    __shared__ short VF[2][2048];                   // V B-frags, dbuf 8KB
    __shared__ __align__(16) short PF[4 * 16 * 76]; // per-wave P, 9.5KB, stride 76
    int tid = threadIdx.x, wave = tid >> 6, lane = tid & 63;
    int cc = lane & 15, quad = lane >> 4;
    short* PFw = PF + wave * 16 * 76;
    int ldsoff = wave * 512;
    float shift2 = -5.6568543f * key_temp[0] * LOG2E_;
    float4v zinit = {shift2, shift2, shift2, shift2};  // folded into QK^T C-operand
    short8 ones;
#pragma unroll
    for (int j = 0; j < 8; ++j) ones[j] = (short)0x3F80;  // bf16 1.0

    // per-lane staging pointers (advance by 2 k-tiles per iter)
    const short* ksrc0 = kb +
        ((size_t)(b * S_LEN + parity * 64 + wave * 16 + (tid & 15)) * 128
         + kvh * 32 + ((tid >> 4) & 3) * 8);
    const short* vsrc0 = vtb +
        ((size_t)((b * 4 + kvh) * 32 + (wave & 1) * 16 + (tid & 15)) * S_LEN
         + parity * 64 + (tid >> 7) * 32 + ((tid >> 4) & 3) * 8);

    for (int half = 0; half < 2; ++half) {
        int qt = half ? (31 - pair) : pair;
        int s0 = qt * 64;
        short8 qfrag = *(const short8*)(qb +
            ((size_t)(b * S_LEN + s0 + wave * 16 + cc) * 512 + h * 32 + quad * 8));
        float4v accO[2];
        accO[0] = (float4v){0.f, 0.f, 0.f, 0.f};
        accO[1] = (float4v){0.f, 0.f, 0.f, 0.f};
        float4v accL = (float4v){0.f, 0.f, 0.f, 0.f};
        int qpos = s0 + wave * 16 + cc;
        const short* ksrc = ksrc0;
        const short* vsrc = vsrc0;
        int nkt = (qt - parity + 2) >> 1;   // #k-tiles this parity covers (0 if qt<parity)

        __syncthreads();   // previous half's readers done before we overwrite buffers
        int cur = 0;
        if (nkt > 0) {     // prologue: stage tile 0
            async_copy16(ksrc, KF[0] + ldsoff);
            async_copy16(vsrc, VF[0] + ldsoff);
            ksrc += 2 * 64 * 128;
            vsrc += 2 * 64;
        }
        for (int it = 0; it < nkt; ++it) {
            int kt = parity + it * 2;
            __syncthreads();   // drains vmcnt: KF/VF[cur] staged; buf[cur^1] readers done
            if (it + 1 < nkt) {  // issue next tile now; lands during compute below
                async_copy16(ksrc, KF[cur ^ 1] + ldsoff);
                async_copy16(vsrc, VF[cur ^ 1] + ldsoff);
                ksrc += 2 * 64 * 128;
                vsrc += 2 * 64;
            }
            const short* KFc = KF[cur];
            const short* VFc = VF[cur];

            // S^T = K·Q^T + shift (C-init): lane holds kpos=chunk*16+quad*4+r, qcol=cc
            float4v st[4];
#pragma unroll
            for (int chunk = 0; chunk < 4; ++chunk) {
                short8 kfrag = *(const short8*)&KFc[chunk * 512 + lane * 8];
                st[chunk] = __builtin_amdgcn_mfma_f32_16x16x32_bf16(kfrag, qfrag, zinit, 0, 0, 0);
            }

            bool diag = (kt == qt);
#pragma unroll
            for (int chunk = 0; chunk < 4; ++chunk) {
                float pv[4];
#pragma unroll
                for (int r = 0; r < 4; ++r) {
                    float e = exp2f(st[chunk][r]);   // scale+shift pre-folded
                    if (diag) {
                        int kpos = kt * 64 + chunk * 16 + quad * 4 + r;
                        e = (kpos <= qpos) ? e : 0.f;
                    }
                    pv[r] = e;
                }
                unsigned u0, u1;   // packed bf16 pairs (RNE)
                asm("v_cvt_pk_bf16_f32 %0, %1, %2" : "=v"(u0) : "v"(pv[0]), "v"(pv[1]));
                asm("v_cvt_pk_bf16_f32 %0, %1, %2" : "=v"(u1) : "v"(pv[2]), "v"(pv[3]));
                *(uint2*)&PFw[cc * 76 + chunk * 16 + quad * 4] = make_uint2(u0, u1);
            }

            // PV: O[q][d] += P·V ; l[q] += P·1  (pfrag A[m=q][k], lane = q + 16*kquad)
#pragma unroll
            for (int kc = 0; kc < 2; ++kc) {
                short8 pfrag = *(const short8*)&PFw[cc * 76 + kc * 32 + quad * 8];
                accL = __builtin_amdgcn_mfma_f32_16x16x32_bf16(pfrag, ones, accL, 0, 0, 0);
#pragma unroll
                for (int dc = 0; dc < 2; ++dc) {
                    short8 vfrag = *(const short8*)&VFc[(kc * 2 + dc) * 512 + lane * 8];
                    accO[dc] = __builtin_amdgcn_mfma_f32_16x16x32_bf16(pfrag, vfrag, accO[dc], 0, 0, 0);
                }
            }
            cur ^= 1;
        }

        // partial epilogue: accL row r holds l for q=quad*4+r (same across cc)
        if (cc == 0) {
#pragma unroll
            for (int r = 0; r < 4; ++r)
                Lsum[((size_t)(b * S_LEN + s0 + wave * 16 + quad * 4 + r)) * 16 + h] = accL[r];
        }
#pragma unroll
        for (int r = 0; r < 4; ++r) {
            float* dst = Onum +
                ((size_t)(b * S_LEN + s0 + wave * 16 + quad * 4 + r) * 512 + h * 32 + cc);
            dst[0]  = accO[0][r];
            dst[16] = accO[1][r];
        }
    }
}

// merge parity partials, divide by l, preout RMS, emit bf16 rows
__global__ __launch_bounds__(256) void rms_preout_bf16(
    const float* __restrict__ OA, const float* __restrict__ OB,
    const float* __restrict__ LA, const float* __restrict__ LB,
    const float* __restrict__ g, short* __restrict__ outb) {
    int row = blockIdx.x;
    __shared__ float scratch[4];
    __shared__ float linv[16];
    int tid = threadIdx.x;
    if (tid < 16)
        linv[tid] = 1.f / (LA[(size_t)row * 16 + tid] + LB[(size_t)row * 16 + tid]);
    __syncthreads();
    float v0 = (OA[(size_t)row * 512 + tid] + OB[(size_t)row * 512 + tid]) * linv[tid >> 5];
    float v1 = (OA[(size_t)row * 512 + tid + 256] + OB[(size_t)row * 512 + tid + 256])
               * linv[(tid + 256) >> 5];
    float ssq = block_reduce_sum_256(v0 * v0 + v1 * v1, scratch);
    float r = rsqrtf(ssq / 512.f + EPS_);
    outb[(size_t)row * 512 + tid]       = f2bs(v0 * r * g[tid]);
    outb[(size_t)row * 512 + tid + 256] = f2bs(v1 * r * g[tid + 256]);
}

extern "C" void kernel_launch(void* const* d_in, const int* in_sizes, int n_in,
                              void* d_out, int out_size, void* d_ws, size_t ws_size,
                              hipStream_t stream) {
    (void)in_sizes; (void)n_in; (void)out_size; (void)ws_size;
    const float* x        = (const float*)d_in[0];
    const float* w_q      = (const float*)d_in[1];
    const float* w_k      = (const float*)d_in[2];
    const float* w_v      = (const float*)d_in[3];
    const float* g_latent = (const float*)d_in[4];
    const float* g_kv     = (const float*)d_in[5];
    const float* conv_q_w = (const float*)d_in[6];
    const float* conv_k_w = (const float*)d_in[7];
    const float* g_conv   = (const float*)d_in[8];
    const float* g_kconv  = (const float*)d_in[9];
    const float* g_postq  = (const float*)d_in[10];
    const float* g_postk  = (const float*)d_in[11];
    const float* key_temp = (const float*)d_in[12];
    const float* g_preout = (const float*)d_in[13];
    const float* w_o      = (const float*)d_in[14];
    float* out = (float*)d_out;

    char* ws = (char*)d_ws;
    const size_t R = NROWS;
    float* qkv   = (float*)ws;                        ws += R * 768 * 4;
    float* qmean = (float*)ws;                        ws += R * 32 * 4;
    float* kmean = (float*)ws;                        ws += R * 32 * 4;
    float* convq = (float*)ws;                        ws += R * 512 * 4;
    float* convk = (float*)ws;                        ws += R * 128 * 4;
    short* qbb   = (short*)ws;                        ws += R * 512 * 2;
    short* kbb   = (short*)ws;                        ws += R * 128 * 2;
    short* vtb   = (short*)ws;                        ws += R * 128 * 2;
    short* xb    = (short*)ws;                        ws += R * 2048 * 2;
    short* wqkvb = (short*)ws;                        ws += 768 * 2048 * 2;
    short* w_ob  = (short*)ws;                        ws += 2048 * 512 * 2;
    // overlays:
    float* qkv2  = convq;          // 25.2MB split-K partial: convq+convk+qbb head,
                                   // all written only AFTER rms_qkv_means consumes it
    float* OnumA = convq;          // 16MB, convq consumed by mix_rows
    float* OnumB = qkv;            // 16MB of 25MB, qkv consumed by convs
    float* LsumA = qmean;          // 0.5MB of 1MB, consumed by mix_rows
    float* LsumB = kmean;
    short* attnb = xb;             // xb dead after QKV gemm

    dim3 blk(256);
    cvt_bf16<<<(NROWS * 2048) / 1024, blk, 0, stream>>>(x, xb, NROWS * 2048);
    cvt_weights<<<2560, blk, 0, stream>>>(w_q, w_k, w_v, w_o, wqkvb, w_ob);

    gemm_bf16_mfma_sk2<<<dim3(6, 64, 2), blk, 0, stream>>>(xb, wqkvb, qkv, qkv2, 768, 2048);
    rms_qkv_means<<<NROWS, blk, 0, stream>>>(qkv, qkv2, g_latent, g_kv, qmean, kmean, vtb);
    causal_conv32<<<dim3(64, 16, 4), blk, 0, stream>>>(qkv, 768, 0, conv_q_w, convq, 512);
    causal_conv32<<<dim3(64, 4, 4), blk, 0, stream>>>(qkv, 768, 512, conv_k_w, convk, 128);
    mix_rows<<<NROWS, blk, 0, stream>>>(convq, convk, qmean, kmean, g_conv, g_kconv,
                                        g_postq, g_postk, key_temp, qbb, kbb);
    attn_mfma<<<dim3(32, 16, 4), blk, 0, stream>>>(qbb, kbb, vtb, OnumA, OnumB,
                                                   LsumA, LsumB, key_temp);
    rms_preout_bf16<<<NROWS, blk, 0, stream>>>(OnumA, OnumB, LsumA, LsumB,
                                               g_preout, attnb);
    gemm_bf16_mfma<<<dim3(16, 64), blk, 0, stream>>>(attnb, w_ob, out, 2048, 512);
}

// Round 6
// 365.703 us; speedup vs baseline: 1.0597x; 1.0597x over previous
//
#include <hip/hip_runtime.h>
#include <hip/hip_bf16.h>
#include <math.h>

constexpr int S_LEN = 2048;
constexpr int B_SZ  = 4;
constexpr int NROWS = B_SZ * S_LEN;   // 8192
constexpr float GAIN_  = 0.25f;
constexpr float EPS_   = 1e-6f;
constexpr float THETA_ = 10000.0f;
constexpr float LOG2E_ = 1.44269504f;

typedef __attribute__((ext_vector_type(8))) short short8;
typedef __attribute__((ext_vector_type(4))) short sshort4;
typedef __attribute__((ext_vector_type(4))) float float4v;

__device__ __forceinline__ short f2bs(float f) {
    __hip_bfloat16 h = __float2bfloat16(f);
    short r;
    __builtin_memcpy(&r, &h, 2);
    return r;
}

__device__ __forceinline__ float bs2f(short s) {
    unsigned u = ((unsigned)(unsigned short)s) << 16;
    float f;
    __builtin_memcpy(&f, &u, 4);
    return f;
}

__device__ __forceinline__ void async_copy16(const short* g, short* l) {
    __builtin_amdgcn_global_load_lds(
        (const __attribute__((address_space(1))) void*)g,
        (__attribute__((address_space(3))) void*)l, 16, 0, 0);
}

// bijective XCD-chunked remap (T1); requires nwg % 8 == 0
__device__ __forceinline__ int xcd_remap(int nwg) {
    int orig = blockIdx.x + gridDim.x * (blockIdx.y + gridDim.y * blockIdx.z);
    return (orig & 7) * (nwg >> 3) + (orig >> 3);
}

__device__ __forceinline__ float block_reduce_sum_256(float v, float* scratch) {
    __syncthreads();
    for (int off = 32; off > 0; off >>= 1)
        v += __shfl_down(v, off, 64);
    int lane = threadIdx.x & 63;
    int wid  = threadIdx.x >> 6;
    if (lane == 0) scratch[wid] = v;
    __syncthreads();
    return scratch[0] + scratch[1] + scratch[2] + scratch[3];
}

// two sums in one shuffle pass: 2 barriers instead of 6
__device__ __forceinline__ void block_reduce_sum2_256(float& a, float& b, float* scratch) {
    __syncthreads();
    for (int off = 32; off > 0; off >>= 1) {
        a += __shfl_down(a, off, 64);
        b += __shfl_down(b, off, 64);
    }
    int lane = threadIdx.x & 63;
    int wid  = threadIdx.x >> 6;
    if (lane == 0) { scratch[wid] = a; scratch[4 + wid] = b; }
    __syncthreads();
    a = scratch[0] + scratch[1] + scratch[2] + scratch[3];
    b = scratch[4] + scratch[5] + scratch[6] + scratch[7];
}

// three sums in one shuffle pass: 2 barriers instead of 9
__device__ __forceinline__ void block_reduce_sum3_256(float& a, float& b, float& c, float* scratch) {
    __syncthreads();
    for (int off = 32; off > 0; off >>= 1) {
        a += __shfl_down(a, off, 64);
        b += __shfl_down(b, off, 64);
        c += __shfl_down(c, off, 64);
    }
    int lane = threadIdx.x & 63;
    int wid  = threadIdx.x >> 6;
    if (lane == 0) { scratch[wid] = a; scratch[4 + wid] = b; scratch[8 + wid] = c; }
    __syncthreads();
    a = scratch[0] + scratch[1] + scratch[2] + scratch[3];
    b = scratch[4] + scratch[5] + scratch[6] + scratch[7];
    c = scratch[8] + scratch[9] + scratch[10] + scratch[11];
}

// fp32 -> bf16 cast, n % 4 == 0
__global__ __launch_bounds__(256) void cvt_bf16(
    const float* __restrict__ src, short* __restrict__ dst, int n) {
    int i = (blockIdx.x * 256 + threadIdx.x) * 4;
    if (i >= n) return;
    float4 v = *(const float4*)(src + i);
    sshort4 o;
    o.x = f2bs(v.x); o.y = f2bs(v.y); o.z = f2bs(v.z); o.w = f2bs(v.w);
    *(sshort4*)(dst + i) = o;
}

// all four weight casts in one launch: wq|wk|wv -> wqkvb (concat), wo -> wob
__global__ __launch_bounds__(256) void cvt_weights(
    const float* __restrict__ wq, const float* __restrict__ wk,
    const float* __restrict__ wv, const float* __restrict__ wo,
    short* __restrict__ wqkvb, short* __restrict__ wob) {
    int i = (blockIdx.x * 256 + threadIdx.x) * 4;
    const float* src;
    short* dst;
    int j;
    if (i < 1048576)      { src = wq; dst = wqkvb + i; j = i; }
    else if (i < 1310720) { src = wk; dst = wqkvb + i; j = i - 1048576; }
    else if (i < 1572864) { src = wv; dst = wqkvb + i; j = i - 1310720; }
    else                  { src = wo; dst = wob + (i - 1572864); j = i - 1572864; }
    float4 v = *(const float4*)(src + j);
    sshort4 o;
    o.x = f2bs(v.x); o.y = f2bs(v.y); o.z = f2bs(v.z); o.w = f2bs(v.w);
    *(sshort4*)dst = o;
}

// RoPE cos/sin table: tab[(s*16+fi)*2] = cos(s*freq_fi), [..+1] = sin
__global__ __launch_bounds__(256) void rope_tab(float* __restrict__ tab) {
    int i = blockIdx.x * 256 + threadIdx.x;   // 0..32767
    int s = i >> 4, fi = i & 15;
    float freq = powf(THETA_, -(float)fi / 16.f);
    float sn, cs;
    sincosf((float)s * freq, &sn, &cs);
    tab[i * 2]     = cs;
    tab[i * 2 + 1] = sn;
}

// C[M x N] fp32 = A[M x K](bf16) @ B[N x K](bf16)^T.  M%128==0, N%128==0, K%32==0.
// XCD-chunked block swizzle for L2 panel reuse.
__global__ __launch_bounds__(256) void gemm_bf16_mfma(
    const short* __restrict__ A, const short* __restrict__ B,
    float* __restrict__ C, int N, int K) {
    __shared__ short As[128 * 32];
    __shared__ short Bs[128 * 32];
    int tid = threadIdx.x;
    int wave = tid >> 6, lane = tid & 63;
    int wg = xcd_remap(gridDim.x * gridDim.y);
    int bx = wg % gridDim.x, by = wg / gridDim.x;
    int m0 = by * 128, n0 = bx * 128;
    int wm = (wave >> 1) * 64, wn = (wave & 1) * 64;
    int mrow = lane & 15, quad = lane >> 4;
    float4v acc[4][4] = {};
    for (int k0 = 0; k0 < K; k0 += 32) {
        __syncthreads();
#pragma unroll
        for (int p = 0; p < 2; ++p) {
            int f = p * 256 + tid;
            int row = f >> 2, ch = (f & 3) * 8;
            const short* ga = A + (size_t)(m0 + row) * K + k0 + ch;
            const short* gb = B + (size_t)(n0 + row) * K + k0 + ch;
            async_copy16(ga, As + p * 2048 + wave * 512);
            async_copy16(gb, Bs + p * 2048 + wave * 512);
        }
        __syncthreads();
        short8 af[4], bf[4];
#pragma unroll
        for (int i = 0; i < 4; ++i)
            af[i] = *(const short8*)&As[(wm + i * 16 + mrow) * 32 + quad * 8];
#pragma unroll
        for (int j = 0; j < 4; ++j)
            bf[j] = *(const short8*)&Bs[(wn + j * 16 + mrow) * 32 + quad * 8];
#pragma unroll
        for (int i = 0; i < 4; ++i)
#pragma unroll
            for (int j = 0; j < 4; ++j)
                acc[i][j] = __builtin_amdgcn_mfma_f32_16x16x32_bf16(af[i], bf[j], acc[i][j], 0, 0, 0);
    }
#pragma unroll
    for (int i = 0; i < 4; ++i)
#pragma unroll
        for (int r = 0; r < 4; ++r) {
            int m = m0 + wm + i * 16 + quad * 4 + r;
            float* crow = C + (size_t)m * N + n0 + wn;
#pragma unroll
            for (int j = 0; j < 4; ++j)
                crow[j * 16 + mrow] = acc[i][j][r];
        }
}

// split-K x2 variant: z selects K-half; z=0 -> C0, z=1 -> C1 (summed later).
// XCD-chunked swizzle over the full 768-block grid.
__global__ __launch_bounds__(256) void gemm_bf16_mfma_sk2(
    const short* __restrict__ A, const short* __restrict__ B,
    float* __restrict__ C0, float* __restrict__ C1, int N, int K) {
    __shared__ short As[128 * 32];
    __shared__ short Bs[128 * 32];
    int tid = threadIdx.x;
    int wave = tid >> 6, lane = tid & 63;
    int wg = xcd_remap(gridDim.x * gridDim.y * gridDim.z);
    int bx = wg % gridDim.x;
    int t  = wg / gridDim.x;
    int by = t % gridDim.y;
    int bz = t / gridDim.y;
    int m0 = by * 128, n0 = bx * 128;
    int wm = (wave >> 1) * 64, wn = (wave & 1) * 64;
    int mrow = lane & 15, quad = lane >> 4;
    int kh = K >> 1;
    int kbeg = bz * kh, kend = kbeg + kh;
    float* __restrict__ C = bz ? C1 : C0;
    float4v acc[4][4] = {};
    for (int k0 = kbeg; k0 < kend; k0 += 32) {
        __syncthreads();
#pragma unroll
        for (int p = 0; p < 2; ++p) {
            int f = p * 256 + tid;
            int row = f >> 2, ch = (f & 3) * 8;
            const short* ga = A + (size_t)(m0 + row) * K + k0 + ch;
            const short* gb = B + (size_t)(n0 + row) * K + k0 + ch;
            async_copy16(ga, As + p * 2048 + wave * 512);
            async_copy16(gb, Bs + p * 2048 + wave * 512);
        }
        __syncthreads();
        short8 af[4], bf[4];
#pragma unroll
        for (int i = 0; i < 4; ++i)
            af[i] = *(const short8*)&As[(wm + i * 16 + mrow) * 32 + quad * 8];
#pragma unroll
        for (int j = 0; j < 4; ++j)
            bf[j] = *(const short8*)&Bs[(wn + j * 16 + mrow) * 32 + quad * 8];
#pragma unroll
        for (int i = 0; i < 4; ++i)
#pragma unroll
            for (int j = 0; j < 4; ++j)
                acc[i][j] = __builtin_amdgcn_mfma_f32_16x16x32_bf16(af[i], bf[j], acc[i][j], 0, 0, 0);
    }
#pragma unroll
    for (int i = 0; i < 4; ++i)
#pragma unroll
        for (int r = 0; r < 4; ++r) {
            int m = m0 + wm + i * 16 + quad * 4 + r;
            float* crow = C + (size_t)m * N + n0 + wn;
#pragma unroll
            for (int j = 0; j < 4; ++j)
                crow[j * 16 + mrow] = acc[i][j][r];
        }
}

// RMS of q (512, g_latent), k (128, g_kv), v (128, g_kv); sums the two split-K
// partials first. q,k stored back to qkv, v stored as bf16 transposed
// vtb[(b*4+kvh)*32+d][s]. Also head-means of q and k.
__global__ __launch_bounds__(256) void rms_qkv_means(
    float* __restrict__ qkv, const float* __restrict__ qkv2,
    const float* __restrict__ g_latent, const float* __restrict__ g_kv,
    float* __restrict__ qmean, float* __restrict__ kmean,
    short* __restrict__ vtb) {
    int row = blockIdx.x;
    int b = row >> 11, s = row & (S_LEN - 1);
    float* p = qkv + (size_t)row * 768;
    const float* p2 = qkv2 + (size_t)row * 768;
    __shared__ float sh[640];
    __shared__ float scratch[12];
    int tid = threadIdx.x;
    float v0 = p[tid] + p2[tid];
    float v1 = p[tid + 256] + p2[tid + 256];
    float v2 = p[tid + 512] + p2[tid + 512];
    float sq = v0 * v0 + v1 * v1;
    float sk = (tid < 128) ? v2 * v2 : 0.f;
    float sv = (tid >= 128) ? v2 * v2 : 0.f;
    block_reduce_sum3_256(sq, sk, sv, scratch);
    float rq = rsqrtf(sq / 512.f + EPS_);
    float q0 = v0 * rq * g_latent[tid];
    float q1 = v1 * rq * g_latent[tid + 256];
    p[tid] = q0; p[tid + 256] = q1;
    sh[tid] = q0; sh[tid + 256] = q1;
    if (tid < 128) {
        float rk = rsqrtf(sk / 128.f + EPS_);
        float kv = v2 * rk * g_kv[tid];
        p[512 + tid] = kv; sh[512 + tid] = kv;
    } else {
        float rv = rsqrtf(sv / 128.f + EPS_);
        float vv = v2 * rv * g_kv[tid - 128];
        int d_full = tid - 128;
        vtb[((size_t)(b * 4 + (d_full >> 5)) * 32 + (d_full & 31)) * S_LEN + s] = f2bs(vv);
    }
    __syncthreads();
    if (tid < 32) {
        float sm = 0.f;
#pragma unroll
        for (int h = 0; h < 16; ++h) sm += sh[h * 32 + tid];
        qmean[(size_t)row * 32 + tid] = sm * (1.f / 16.f);
    } else if (tid < 64) {
        int d = tid - 32;
        float sm = 0.f;
#pragma unroll
        for (int h = 0; h < 4; ++h) sm += sh[512 + h * 32 + d];
        kmean[(size_t)row * 32 + d] = sm * 0.25f;
    }
}

// Grouped causal conv, 32 in / 32 out channels per group, K=3, left pad 2.
__global__ __launch_bounds__(256) void causal_conv32(
    const float* __restrict__ in, int ldin, int inoff,
    const float* __restrict__ w, float* __restrict__ out, int C) {
    int b = blockIdx.z, g = blockIdx.y, s0 = blockIdx.x * 32;
    __shared__ float wsh[32][3][32];   // [ic][tap][oc]
    __shared__ float ish[34][33];      // [pos][ic]
    int tid = threadIdx.x;
    for (int i = tid; i < 32 * 96; i += 256) {
        int oc = i / 96, r = i % 96;
        wsh[r / 3][r % 3][oc] = w[(size_t)(g * 32 + oc) * 96 + r];
    }
    for (int i = tid; i < 34 * 32; i += 256) {
        int pp = i >> 5, ic = i & 31;
        int s = s0 - 2 + pp;
        ish[pp][ic] = (s >= 0) ? in[((size_t)b * S_LEN + s) * ldin + inoff + g * 32 + ic] : 0.f;
    }
    __syncthreads();
    int sl = tid >> 3, oc0 = (tid & 7) * 4;
    float acc[4] = {0.f, 0.f, 0.f, 0.f};
    for (int ic = 0; ic < 32; ++ic) {
        float x0 = ish[sl][ic], x1 = ish[sl + 1][ic], x2 = ish[sl + 2][ic];
#pragma unroll
        for (int j = 0; j < 4; ++j)
            acc[j] += x0 * wsh[ic][0][oc0 + j] + x1 * wsh[ic][1][oc0 + j] + x2 * wsh[ic][2][oc0 + j];
    }
    float* orow = out + ((size_t)b * S_LEN + s0 + sl) * C + g * 32 + oc0;
    orow[0] = acc[0]; orow[1] = acc[1]; orow[2] = acc[2]; orow[3] = acc[3];
}

// Per-row: conv-RMS, + GAIN*mean-mix, post-RMS, per-head L2 norm, RoPE (table).
// Writes final q (512, pre-scaled by attention scale AND log2(e)) and k (128) as bf16.
__global__ __launch_bounds__(256) void mix_rows(
    const float* __restrict__ convq, const float* __restrict__ convk,
    const float* __restrict__ qmean, const float* __restrict__ kmean,
    const float* __restrict__ g_conv, const float* __restrict__ g_kconv,
    const float* __restrict__ g_postq, const float* __restrict__ g_postk,
    const float* __restrict__ key_temp, const float* __restrict__ rtab,
    short* __restrict__ qb, short* __restrict__ kb) {
    int row = blockIdx.x;
    int s = row & (S_LEN - 1);
    int tid = threadIdx.x;
    __shared__ float sh[640];
    __shared__ float scratch[8];
    __shared__ float hscale[20];
    float q0 = convq[(size_t)row * 512 + tid];
    float q1 = convq[(size_t)row * 512 + tid + 256];
    float k0 = (tid < 128) ? convk[(size_t)row * 128 + tid] : 0.f;
    float ssq = q0 * q0 + q1 * q1;
    float ssk = k0 * k0;
    block_reduce_sum2_256(ssq, ssk, scratch);
    float r1  = rsqrtf(ssq / 512.f + EPS_);
    float rk1 = rsqrtf(ssk / 128.f + EPS_);
    float km = kmean[(size_t)row * 32 + (tid & 31)];
    float a0 = q0 * r1 * g_conv[tid] + GAIN_ * km;
    float a1 = q1 * r1 * g_conv[tid + 256] + GAIN_ * km;
    float ak = 0.f;
    if (tid < 128) ak = k0 * rk1 * g_kconv[tid] + GAIN_ * qmean[(size_t)row * 32 + (tid & 31)];
    float ssq2 = a0 * a0 + a1 * a1;
    float ssk2 = ak * ak;
    block_reduce_sum2_256(ssq2, ssk2, scratch);
    float r2  = rsqrtf(ssq2 / 512.f + EPS_);
    float rk2 = rsqrtf(ssk2 / 128.f + EPS_);
    sh[tid] = a0 * r2 * g_postq[tid];
    sh[tid + 256] = a1 * r2 * g_postq[tid + 256];
    if (tid < 128) sh[512 + tid] = ak * rk2 * g_postk[tid];
    __syncthreads();
    if (tid < 16) {
        float ssh = 0.f;
        for (int d = 0; d < 32; ++d) { float x = sh[tid * 32 + d]; ssh += x * x; }
        // sqrt(32)*(1/sqrt(32)) == 1: attention scale folded into q.
        // LOG2E folded too so attn softmax is a bare exp2(st + shift).
        hscale[tid] = LOG2E_ / fmaxf(sqrtf(ssh), 1e-12f);
    } else if (tid < 20) {
        int h = tid - 16;
        float ssh = 0.f;
        for (int d = 0; d < 32; ++d) { float x = sh[512 + h * 32 + d]; ssh += x * x; }
        hscale[tid] = sqrtf(32.f) / fmaxf(sqrtf(ssh), 1e-12f) * key_temp[0];
    }
    __syncthreads();
    {   // q RoPE: 256 pairs, packed 4B store
        int i0 = tid * 2;
        int h = i0 >> 5;
        int fi = (i0 & 31) >> 1;
        float sc = hscale[h];
        float x1 = sh[i0] * sc, x2 = sh[i0 + 1] * sc;
        float2 cssn = *(const float2*)&rtab[((size_t)s * 16 + fi) * 2];
        float cs = cssn.x, sn = cssn.y;
        unsigned lo = (unsigned short)f2bs(x1 * cs - x2 * sn);
        unsigned hi = (unsigned short)f2bs(x1 * sn + x2 * cs);
        *(unsigned*)(qb + (size_t)row * 512 + i0) = lo | (hi << 16);
    }
    if (tid < 64) {  // k RoPE: 64 pairs, packed 4B store
        int i0 = tid * 2;
        int h = i0 >> 5;
        int fi = (i0 & 31) >> 1;
        float sc = hscale[16 + h];
        float x1 = sh[512 + i0] * sc, x2 = sh[512 + i0 + 1] * sc;
        float2 cssn = *(const float2*)&rtab[((size_t)s * 16 + fi) * 2];
        float cs = cssn.x, sn = cssn.y;
        unsigned lo = (unsigned short)f2bs(x1 * cs - x2 * sn);
        unsigned hi = (unsigned short)f2bs(x1 * sn + x2 * cs);
        *(unsigned*)(kb + (size_t)row * 128 + i0) = lo | (hi << 16);
    }
}

// MFMA flash attention, qt-paired (balanced), NO parity split: each block owns
// (q-tile pair, head, batch) and walks ALL k-tiles, so it can divide by l
// in-kernel and emit bf16 O directly (no fp32 numerator round-trip).
// VALU-lean softmax: shift in MFMA C-init, LOG2E folded into q, cvt_pk pack,
// row-sum l via ones-B MFMA. PF stride 72 (R2-verified fastest).
__global__ __launch_bounds__(256) void attn_mfma(
    const short* __restrict__ qb, const short* __restrict__ kb,
    const short* __restrict__ vtb, short* __restrict__ obf,
    const float* __restrict__ key_temp) {
    int pair = blockIdx.x, h = blockIdx.y, b = blockIdx.z;
    int kvh = h >> 2;
    __shared__ short KF[2][2048];                   // K A-frags, dbuf 8KB
    __shared__ short VF[2][2048];                   // V B-frags, dbuf 8KB
    __shared__ __align__(16) short PF[4 * 16 * 72]; // per-wave P, 9KB
    int tid = threadIdx.x, wave = tid >> 6, lane = tid & 63;
    int cc = lane & 15, quad = lane >> 4;
    short* PFw = PF + wave * 16 * 72;
    int ldsoff = wave * 512;
    float shift2 = -5.6568543f * key_temp[0] * LOG2E_;
    float4v zinit = {shift2, shift2, shift2, shift2};  // folded into QK^T C-operand
    short8 ones;
#pragma unroll
    for (int j = 0; j < 8; ++j) ones[j] = (short)0x3F80;  // bf16 1.0

    // per-lane staging pointers (advance by 1 k-tile per iter)
    const short* ksrc0 = kb +
        ((size_t)(b * S_LEN + wave * 16 + (tid & 15)) * 128
         + kvh * 32 + ((tid >> 4) & 3) * 8);
    const short* vsrc0 = vtb +
        ((size_t)((b * 4 + kvh) * 32 + (wave & 1) * 16 + (tid & 15)) * S_LEN
         + (tid >> 7) * 32 + ((tid >> 4) & 3) * 8);

    for (int half = 0; half < 2; ++half) {
        int qt = half ? (31 - pair) : pair;
        int s0 = qt * 64;
        short8 qfrag = *(const short8*)(qb +
            ((size_t)(b * S_LEN + s0 + wave * 16 + cc) * 512 + h * 32 + quad * 8));
        float4v accO[2];
        accO[0] = (float4v){0.f, 0.f, 0.f, 0.f};
        accO[1] = (float4v){0.f, 0.f, 0.f, 0.f};
        float4v accL = (float4v){0.f, 0.f, 0.f, 0.f};
        int qpos = s0 + wave * 16 + cc;
        const short* ksrc = ksrc0;
        const short* vsrc = vsrc0;
        int nkt = qt + 1;

        __syncthreads();   // previous half's readers done before we overwrite buffers
        int cur = 0;
        // prologue: stage tile 0
        async_copy16(ksrc, KF[0] + ldsoff);
        async_copy16(vsrc, VF[0] + ldsoff);
        ksrc += 64 * 128;
        vsrc += 64;
        for (int kt = 0; kt < nkt; ++kt) {
            __syncthreads();   // drains vmcnt: KF/VF[cur] staged; buf[cur^1] readers done
            if (kt + 1 < nkt) {  // issue next tile now; lands during compute below
                async_copy16(ksrc, KF[cur ^ 1] + ldsoff);
                async_copy16(vsrc, VF[cur ^ 1] + ldsoff);
                ksrc += 64 * 128;
                vsrc += 64;
            }
            const short* KFc = KF[cur];
            const short* VFc = VF[cur];

            // S^T = K·Q^T + shift (C-init): lane holds kpos=chunk*16+quad*4+r, qcol=cc
            float4v st[4];
#pragma unroll
            for (int chunk = 0; chunk < 4; ++chunk) {
                short8 kfrag = *(const short8*)&KFc[chunk * 512 + lane * 8];
                st[chunk] = __builtin_amdgcn_mfma_f32_16x16x32_bf16(kfrag, qfrag, zinit, 0, 0, 0);
            }

            bool diag = (kt == qt);
#pragma unroll
            for (int chunk = 0; chunk < 4; ++chunk) {
                float pv[4];
#pragma unroll
                for (int r = 0; r < 4; ++r) {
                    float e = exp2f(st[chunk][r]);   // scale+shift pre-folded
                    if (diag) {
                        int kpos = kt * 64 + chunk * 16 + quad * 4 + r;
                        e = (kpos <= qpos) ? e : 0.f;
                    }
                    pv[r] = e;
                }
                unsigned u0, u1;   // packed bf16 pairs (RNE)
                asm("v_cvt_pk_bf16_f32 %0, %1, %2" : "=v"(u0) : "v"(pv[0]), "v"(pv[1]));
                asm("v_cvt_pk_bf16_f32 %0, %1, %2" : "=v"(u1) : "v"(pv[2]), "v"(pv[3]));
                *(uint2*)&PFw[cc * 72 + chunk * 16 + quad * 4] = make_uint2(u0, u1);
            }

            // PV: O[q][d] += P·V ; l[q] += P·1  (pfrag A[m=q][k], lane = q + 16*kquad)
#pragma unroll
            for (int kc = 0; kc < 2; ++kc) {
                short8 pfrag = *(const short8*)&PFw[cc * 72 + kc * 32 + quad * 8];
                accL = __builtin_amdgcn_mfma_f32_16x16x32_bf16(pfrag, ones, accL, 0, 0, 0);
#pragma unroll
                for (int dc = 0; dc < 2; ++dc) {
                    short8 vfrag = *(const short8*)&VFc[(kc * 2 + dc) * 512 + lane * 8];
                    accO[dc] = __builtin_amdgcn_mfma_f32_16x16x32_bf16(pfrag, vfrag, accO[dc], 0, 0, 0);
                }
            }
            cur ^= 1;
        }

        // epilogue: accL[r] = l for q=quad*4+r (same lane as accO rows); divide,
        // emit bf16. O layout: row q, d = dc*16 + cc.
#pragma unroll
        for (int r = 0; r < 4; ++r) {
            float linv = 1.f / accL[r];
            short* dst = obf +
                ((size_t)(b * S_LEN + s0 + wave * 16 + quad * 4 + r) * 512 + h * 32 + cc);
            dst[0]  = f2bs(accO[0][r] * linv);
            dst[16] = f2bs(accO[1][r] * linv);
        }
    }
}

// preout RMS on bf16 O rows, emit bf16 rows for the out GEMM
__global__ __launch_bounds__(256) void rms_preout_bf16(
    const short* __restrict__ obf, const float* __restrict__ g,
    short* __restrict__ outb) {
    int row = blockIdx.x;
    __shared__ float scratch[4];
    int tid = threadIdx.x;
    unsigned pk = *(const unsigned*)(obf + (size_t)row * 512 + tid * 2);
    float v0 = bs2f((short)(pk & 0xFFFF));
    float v1 = bs2f((short)(pk >> 16));
    float ssq = block_reduce_sum_256(v0 * v0 + v1 * v1, scratch);
    float r = rsqrtf(ssq / 512.f + EPS_);
    unsigned lo = (unsigned short)f2bs(v0 * r * g[tid * 2]);
    unsigned hi = (unsigned short)f2bs(v1 * r * g[tid * 2 + 1]);
    *(unsigned*)(outb + (size_t)row * 512 + tid * 2) = lo | (hi << 16);
}

extern "C" void kernel_launch(void* const* d_in, const int* in_sizes, int n_in,
                              void* d_out, int out_size, void* d_ws, size_t ws_size,
                              hipStream_t stream) {
    (void)in_sizes; (void)n_in; (void)out_size; (void)ws_size;
    const float* x        = (const float*)d_in[0];
    const float* w_q      = (const float*)d_in[1];
    const float* w_k      = (const float*)d_in[2];
    const float* w_v      = (const float*)d_in[3];
    const float* g_latent = (const float*)d_in[4];
    const float* g_kv     = (const float*)d_in[5];
    const float* conv_q_w = (const float*)d_in[6];
    const float* conv_k_w = (const float*)d_in[7];
    const float* g_conv   = (const float*)d_in[8];
    const float* g_kconv  = (const float*)d_in[9];
    const float* g_postq  = (const float*)d_in[10];
    const float* g_postk  = (const float*)d_in[11];
    const float* key_temp = (const float*)d_in[12];
    const float* g_preout = (const float*)d_in[13];
    const float* w_o      = (const float*)d_in[14];
    float* out = (float*)d_out;

    char* ws = (char*)d_ws;
    const size_t R = NROWS;
    float* qkv   = (float*)ws;                        ws += R * 768 * 4;
    float* qmean = (float*)ws;                        ws += R * 32 * 4;
    float* kmean = (float*)ws;                        ws += R * 32 * 4;
    float* convq = (float*)ws;                        ws += R * 512 * 4;
    float* convk = (float*)ws;                        ws += R * 128 * 4;
    short* qbb   = (short*)ws;                        ws += R * 512 * 2;
    short* kbb   = (short*)ws;                        ws += R * 128 * 2;
    short* vtb   = (short*)ws;                        ws += R * 128 * 2;
    short* xb    = (short*)ws;                        ws += R * 2048 * 2;
    short* wqkvb = (short*)ws;                        ws += 768 * 2048 * 2;
    short* w_ob  = (short*)ws;                        ws += 2048 * 512 * 2;
    float* rtab  = (float*)ws;                        ws += 2048 * 16 * 2 * 4;
    // overlays:
    float* qkv2  = convq;          // 25.2MB split-K partial: convq+convk+qbb head,
                                   // all written only AFTER rms_qkv_means consumes it
    short* obf   = xb;             // xb dead after QKV gemm: bf16 O numerator/l
    short* attnb = xb + R * 512;   // preout-RMS'd rows for the out GEMM

    dim3 blk(256);
    rope_tab<<<128, blk, 0, stream>>>(rtab);
    cvt_bf16<<<(NROWS * 2048) / 1024, blk, 0, stream>>>(x, xb, NROWS * 2048);
    cvt_weights<<<2560, blk, 0, stream>>>(w_q, w_k, w_v, w_o, wqkvb, w_ob);

    gemm_bf16_mfma_sk2<<<dim3(6, 64, 2), blk, 0, stream>>>(xb, wqkvb, qkv, qkv2, 768, 2048);
    rms_qkv_means<<<NROWS, blk, 0, stream>>>(qkv, qkv2, g_latent, g_kv, qmean, kmean, vtb);
    causal_conv32<<<dim3(64, 16, 4), blk, 0, stream>>>(qkv, 768, 0, conv_q_w, convq, 512);
    causal_conv32<<<dim3(64, 4, 4), blk, 0, stream>>>(qkv, 768, 512, conv_k_w, convk, 128);
    mix_rows<<<NROWS, blk, 0, stream>>>(convq, convk, qmean, kmean, g_conv, g_kconv,
                                        g_postq, g_postk, key_temp, rtab, qbb, kbb);
    attn_mfma<<<dim3(16, 16, 4), blk, 0, stream>>>(qbb, kbb, vtb, obf, key_temp);
    rms_preout_bf16<<<NROWS, blk, 0, stream>>>(obf, g_preout, attnb);
    gemm_bf16_mfma<<<dim3(16, 64), blk, 0, stream>>>(attnb, w_ob, out, 2048, 512);
}

// Round 7
// 361.312 us; speedup vs baseline: 1.0726x; 1.0122x over previous
//
#include <hip/hip_runtime.h>
#include <hip/hip_bf16.h>
#include <math.h>

constexpr int S_LEN = 2048;
constexpr int B_SZ  = 4;
constexpr int NROWS = B_SZ * S_LEN;   // 8192
constexpr float GAIN_  = 0.25f;
constexpr float EPS_   = 1e-6f;
constexpr float THETA_ = 10000.0f;
constexpr float LOG2E_ = 1.44269504f;

typedef __attribute__((ext_vector_type(8))) short short8;
typedef __attribute__((ext_vector_type(4))) short sshort4;
typedef __attribute__((ext_vector_type(4))) float float4v;

__device__ __forceinline__ short f2bs(float f) {
    __hip_bfloat16 h = __float2bfloat16(f);
    short r;
    __builtin_memcpy(&r, &h, 2);
    return r;
}

__device__ __forceinline__ float bs2f(short s) {
    unsigned u = ((unsigned)(unsigned short)s) << 16;
    float f;
    __builtin_memcpy(&f, &u, 4);
    return f;
}

__device__ __forceinline__ void async_copy16(const short* g, short* l) {
    __builtin_amdgcn_global_load_lds(
        (const __attribute__((address_space(1))) void*)g,
        (__attribute__((address_space(3))) void*)l, 16, 0, 0);
}

// bijective XCD-chunked remap (T1); requires nwg % 8 == 0
__device__ __forceinline__ int xcd_remap(int nwg) {
    int orig = blockIdx.x + gridDim.x * (blockIdx.y + gridDim.y * blockIdx.z);
    return (orig & 7) * (nwg >> 3) + (orig >> 3);
}

__device__ __forceinline__ float block_reduce_sum_256(float v, float* scratch) {
    __syncthreads();
    for (int off = 32; off > 0; off >>= 1)
        v += __shfl_down(v, off, 64);
    int lane = threadIdx.x & 63;
    int wid  = threadIdx.x >> 6;
    if (lane == 0) scratch[wid] = v;
    __syncthreads();
    return scratch[0] + scratch[1] + scratch[2] + scratch[3];
}

// two sums in one shuffle pass: 2 barriers instead of 6
__device__ __forceinline__ void block_reduce_sum2_256(float& a, float& b, float* scratch) {
    __syncthreads();
    for (int off = 32; off > 0; off >>= 1) {
        a += __shfl_down(a, off, 64);
        b += __shfl_down(b, off, 64);
    }
    int lane = threadIdx.x & 63;
    int wid  = threadIdx.x >> 6;
    if (lane == 0) { scratch[wid] = a; scratch[4 + wid] = b; }
    __syncthreads();
    a = scratch[0] + scratch[1] + scratch[2] + scratch[3];
    b = scratch[4] + scratch[5] + scratch[6] + scratch[7];
}

// three sums in one shuffle pass: 2 barriers instead of 9
__device__ __forceinline__ void block_reduce_sum3_256(float& a, float& b, float& c, float* scratch) {
    __syncthreads();
    for (int off = 32; off > 0; off >>= 1) {
        a += __shfl_down(a, off, 64);
        b += __shfl_down(b, off, 64);
        c += __shfl_down(c, off, 64);
    }
    int lane = threadIdx.x & 63;
    int wid  = threadIdx.x >> 6;
    if (lane == 0) { scratch[wid] = a; scratch[4 + wid] = b; scratch[8 + wid] = c; }
    __syncthreads();
    a = scratch[0] + scratch[1] + scratch[2] + scratch[3];
    b = scratch[4] + scratch[5] + scratch[6] + scratch[7];
    c = scratch[8] + scratch[9] + scratch[10] + scratch[11];
}

// Fused prep: x fp32->bf16 cast (blocks 0..16383), weight casts (16384..18943),
// RoPE cos/sin table (18944..19071).
__global__ __launch_bounds__(256) void cvt_all(
    const float* __restrict__ x, short* __restrict__ xb,
    const float* __restrict__ wq, const float* __restrict__ wk,
    const float* __restrict__ wv, const float* __restrict__ wo,
    short* __restrict__ wqkvb, short* __restrict__ wob,
    float* __restrict__ rtab) {
    int blk = blockIdx.x;
    int tid = threadIdx.x;
    if (blk < 16384) {
        int i = (blk * 256 + tid) * 4;
        float4 v = *(const float4*)(x + i);
        sshort4 o;
        o.x = f2bs(v.x); o.y = f2bs(v.y); o.z = f2bs(v.z); o.w = f2bs(v.w);
        *(sshort4*)(xb + i) = o;
    } else if (blk < 16384 + 2560) {
        int i = ((blk - 16384) * 256 + tid) * 4;
        const float* src;
        short* dst;
        int j;
        if (i < 1048576)      { src = wq; dst = wqkvb + i; j = i; }
        else if (i < 1310720) { src = wk; dst = wqkvb + i; j = i - 1048576; }
        else if (i < 1572864) { src = wv; dst = wqkvb + i; j = i - 1310720; }
        else                  { src = wo; dst = wob + (i - 1572864); j = i - 1572864; }
        float4 v = *(const float4*)(src + j);
        sshort4 o;
        o.x = f2bs(v.x); o.y = f2bs(v.y); o.z = f2bs(v.z); o.w = f2bs(v.w);
        *(sshort4*)dst = o;
    } else {
        int i = (blk - 16384 - 2560) * 256 + tid;   // 0..32767
        int s = i >> 4, fi = i & 15;
        float freq = powf(THETA_, -(float)fi / 16.f);
        float sn, cs;
        sincosf((float)s * freq, &sn, &cs);
        rtab[i * 2]     = cs;
        rtab[i * 2 + 1] = sn;
    }
}

// C[M x N] fp32 = A[M x K](bf16) @ B[N x K](bf16)^T.  M%128==0, N%128==0, K%32==0.
// XCD-chunked block swizzle for L2 panel reuse.
__global__ __launch_bounds__(256) void gemm_bf16_mfma(
    const short* __restrict__ A, const short* __restrict__ B,
    float* __restrict__ C, int N, int K) {
    __shared__ short As[128 * 32];
    __shared__ short Bs[128 * 32];
    int tid = threadIdx.x;
    int wave = tid >> 6, lane = tid & 63;
    int wg = xcd_remap(gridDim.x * gridDim.y);
    int bx = wg % gridDim.x, by = wg / gridDim.x;
    int m0 = by * 128, n0 = bx * 128;
    int wm = (wave >> 1) * 64, wn = (wave & 1) * 64;
    int mrow = lane & 15, quad = lane >> 4;
    float4v acc[4][4] = {};
    for (int k0 = 0; k0 < K; k0 += 32) {
        __syncthreads();
#pragma unroll
        for (int p = 0; p < 2; ++p) {
            int f = p * 256 + tid;
            int row = f >> 2, ch = (f & 3) * 8;
            const short* ga = A + (size_t)(m0 + row) * K + k0 + ch;
            const short* gb = B + (size_t)(n0 + row) * K + k0 + ch;
            async_copy16(ga, As + p * 2048 + wave * 512);
            async_copy16(gb, Bs + p * 2048 + wave * 512);
        }
        __syncthreads();
        short8 af[4], bf[4];
#pragma unroll
        for (int i = 0; i < 4; ++i)
            af[i] = *(const short8*)&As[(wm + i * 16 + mrow) * 32 + quad * 8];
#pragma unroll
        for (int j = 0; j < 4; ++j)
            bf[j] = *(const short8*)&Bs[(wn + j * 16 + mrow) * 32 + quad * 8];
#pragma unroll
        for (int i = 0; i < 4; ++i)
#pragma unroll
            for (int j = 0; j < 4; ++j)
                acc[i][j] = __builtin_amdgcn_mfma_f32_16x16x32_bf16(af[i], bf[j], acc[i][j], 0, 0, 0);
    }
#pragma unroll
    for (int i = 0; i < 4; ++i)
#pragma unroll
        for (int r = 0; r < 4; ++r) {
            int m = m0 + wm + i * 16 + quad * 4 + r;
            float* crow = C + (size_t)m * N + n0 + wn;
#pragma unroll
            for (int j = 0; j < 4; ++j)
                crow[j * 16 + mrow] = acc[i][j][r];
        }
}

// split-K x2 variant: z selects K-half; z=0 -> C0, z=1 -> C1 (summed later).
// XCD-chunked swizzle over the full 768-block grid.
__global__ __launch_bounds__(256) void gemm_bf16_mfma_sk2(
    const short* __restrict__ A, const short* __restrict__ B,
    float* __restrict__ C0, float* __restrict__ C1, int N, int K) {
    __shared__ short As[128 * 32];
    __shared__ short Bs[128 * 32];
    int tid = threadIdx.x;
    int wave = tid >> 6, lane = tid & 63;
    int wg = xcd_remap(gridDim.x * gridDim.y * gridDim.z);
    int bx = wg % gridDim.x;
    int t  = wg / gridDim.x;
    int by = t % gridDim.y;
    int bz = t / gridDim.y;
    int m0 = by * 128, n0 = bx * 128;
    int wm = (wave >> 1) * 64, wn = (wave & 1) * 64;
    int mrow = lane & 15, quad = lane >> 4;
    int kh = K >> 1;
    int kbeg = bz * kh, kend = kbeg + kh;
    float* __restrict__ C = bz ? C1 : C0;
    float4v acc[4][4] = {};
    for (int k0 = kbeg; k0 < kend; k0 += 32) {
        __syncthreads();
#pragma unroll
        for (int p = 0; p < 2; ++p) {
            int f = p * 256 + tid;
            int row = f >> 2, ch = (f & 3) * 8;
            const short* ga = A + (size_t)(m0 + row) * K + k0 + ch;
            const short* gb = B + (size_t)(n0 + row) * K + k0 + ch;
            async_copy16(ga, As + p * 2048 + wave * 512);
            async_copy16(gb, Bs + p * 2048 + wave * 512);
        }
        __syncthreads();
        short8 af[4], bf[4];
#pragma unroll
        for (int i = 0; i < 4; ++i)
            af[i] = *(const short8*)&As[(wm + i * 16 + mrow) * 32 + quad * 8];
#pragma unroll
        for (int j = 0; j < 4; ++j)
            bf[j] = *(const short8*)&Bs[(wn + j * 16 + mrow) * 32 + quad * 8];
#pragma unroll
        for (int i = 0; i < 4; ++i)
#pragma unroll
            for (int j = 0; j < 4; ++j)
                acc[i][j] = __builtin_amdgcn_mfma_f32_16x16x32_bf16(af[i], bf[j], acc[i][j], 0, 0, 0);
    }
#pragma unroll
    for (int i = 0; i < 4; ++i)
#pragma unroll
        for (int r = 0; r < 4; ++r) {
            int m = m0 + wm + i * 16 + quad * 4 + r;
            float* crow = C + (size_t)m * N + n0 + wn;
#pragma unroll
            for (int j = 0; j < 4; ++j)
                crow[j * 16 + mrow] = acc[i][j][r];
        }
}

// RMS of q (512, g_latent), k (128, g_kv), v (128, g_kv); sums the two split-K
// partials first. q,k stored back to qkv, v stored as bf16 transposed
// vtb[(b*4+kvh)*32+d][s]. Also head-means of q and k.
__global__ __launch_bounds__(256) void rms_qkv_means(
    float* __restrict__ qkv, const float* __restrict__ qkv2,
    const float* __restrict__ g_latent, const float* __restrict__ g_kv,
    float* __restrict__ qmean, float* __restrict__ kmean,
    short* __restrict__ vtb) {
    int row = blockIdx.x;
    int b = row >> 11, s = row & (S_LEN - 1);
    float* p = qkv + (size_t)row * 768;
    const float* p2 = qkv2 + (size_t)row * 768;
    __shared__ float sh[640];
    __shared__ float scratch[12];
    int tid = threadIdx.x;
    float v0 = p[tid] + p2[tid];
    float v1 = p[tid + 256] + p2[tid + 256];
    float v2 = p[tid + 512] + p2[tid + 512];
    float sq = v0 * v0 + v1 * v1;
    float sk = (tid < 128) ? v2 * v2 : 0.f;
    float sv = (tid >= 128) ? v2 * v2 : 0.f;
    block_reduce_sum3_256(sq, sk, sv, scratch);
    float rq = rsqrtf(sq / 512.f + EPS_);
    float q0 = v0 * rq * g_latent[tid];
    float q1 = v1 * rq * g_latent[tid + 256];
    p[tid] = q0; p[tid + 256] = q1;
    sh[tid] = q0; sh[tid + 256] = q1;
    if (tid < 128) {
        float rk = rsqrtf(sk / 128.f + EPS_);
        float kv = v2 * rk * g_kv[tid];
        p[512 + tid] = kv; sh[512 + tid] = kv;
    } else {
        float rv = rsqrtf(sv / 128.f + EPS_);
        float vv = v2 * rv * g_kv[tid - 128];
        int d_full = tid - 128;
        vtb[((size_t)(b * 4 + (d_full >> 5)) * 32 + (d_full & 31)) * S_LEN + s] = f2bs(vv);
    }
    __syncthreads();
    if (tid < 32) {
        float sm = 0.f;
#pragma unroll
        for (int h = 0; h < 16; ++h) sm += sh[h * 32 + tid];
        qmean[(size_t)row * 32 + tid] = sm * (1.f / 16.f);
    } else if (tid < 64) {
        int d = tid - 32;
        float sm = 0.f;
#pragma unroll
        for (int h = 0; h < 4; ++h) sm += sh[512 + h * 32 + d];
        kmean[(size_t)row * 32 + d] = sm * 0.25f;
    }
}

// Grouped causal conv, 32 in / 32 out channels per group, K=3, left pad 2.
__device__ __forceinline__ void conv32_body(
    const float* __restrict__ in, int ldin, int inoff,
    const float* __restrict__ w, float* __restrict__ out, int C, int g) {
    int b = blockIdx.z, s0 = blockIdx.x * 32;
    __shared__ float wsh[32][3][32];   // [ic][tap][oc]
    __shared__ float ish[34][33];      // [pos][ic]
    int tid = threadIdx.x;
    for (int i = tid; i < 32 * 96; i += 256) {
        int oc = i / 96, r = i % 96;
        wsh[r / 3][r % 3][oc] = w[(size_t)(g * 32 + oc) * 96 + r];
    }
    for (int i = tid; i < 34 * 32; i += 256) {
        int pp = i >> 5, ic = i & 31;
        int s = s0 - 2 + pp;
        ish[pp][ic] = (s >= 0) ? in[((size_t)b * S_LEN + s) * ldin + inoff + g * 32 + ic] : 0.f;
    }
    __syncthreads();
    int sl = tid >> 3, oc0 = (tid & 7) * 4;
    float acc[4] = {0.f, 0.f, 0.f, 0.f};
    for (int ic = 0; ic < 32; ++ic) {
        float x0 = ish[sl][ic], x1 = ish[sl + 1][ic], x2 = ish[sl + 2][ic];
#pragma unroll
        for (int j = 0; j < 4; ++j)
            acc[j] += x0 * wsh[ic][0][oc0 + j] + x1 * wsh[ic][1][oc0 + j] + x2 * wsh[ic][2][oc0 + j];
    }
    float* orow = out + ((size_t)b * S_LEN + s0 + sl) * C + g * 32 + oc0;
    orow[0] = acc[0]; orow[1] = acc[1]; orow[2] = acc[2]; orow[3] = acc[3];
}

// merged q-conv (y<16) and k-conv (y>=16) in one launch
__global__ __launch_bounds__(256) void causal_conv_all(
    const float* __restrict__ qkv, const float* __restrict__ conv_q_w,
    const float* __restrict__ conv_k_w, float* __restrict__ convq,
    float* __restrict__ convk) {
    int y = blockIdx.y;
    if (y < 16) conv32_body(qkv, 768, 0,   conv_q_w, convq, 512, y);
    else        conv32_body(qkv, 768, 512, conv_k_w, convk, 128, y - 16);
}

// Per-row: conv-RMS, + GAIN*mean-mix, post-RMS, per-head L2 norm, RoPE (table).
// Writes final q (512, pre-scaled by attention scale AND log2(e)) and k (128) as bf16.
__global__ __launch_bounds__(256) void mix_rows(
    const float* __restrict__ convq, const float* __restrict__ convk,
    const float* __restrict__ qmean, const float* __restrict__ kmean,
    const float* __restrict__ g_conv, const float* __restrict__ g_kconv,
    const float* __restrict__ g_postq, const float* __restrict__ g_postk,
    const float* __restrict__ key_temp, const float* __restrict__ rtab,
    short* __restrict__ qb, short* __restrict__ kb) {
    int row = blockIdx.x;
    int s = row & (S_LEN - 1);
    int tid = threadIdx.x;
    __shared__ float sh[640];
    __shared__ float scratch[8];
    __shared__ float hscale[20];
    float q0 = convq[(size_t)row * 512 + tid];
    float q1 = convq[(size_t)row * 512 + tid + 256];
    float k0 = (tid < 128) ? convk[(size_t)row * 128 + tid] : 0.f;
    float ssq = q0 * q0 + q1 * q1;
    float ssk = k0 * k0;
    block_reduce_sum2_256(ssq, ssk, scratch);
    float r1  = rsqrtf(ssq / 512.f + EPS_);
    float rk1 = rsqrtf(ssk / 128.f + EPS_);
    float km = kmean[(size_t)row * 32 + (tid & 31)];
    float a0 = q0 * r1 * g_conv[tid] + GAIN_ * km;
    float a1 = q1 * r1 * g_conv[tid + 256] + GAIN_ * km;
    float ak = 0.f;
    if (tid < 128) ak = k0 * rk1 * g_kconv[tid] + GAIN_ * qmean[(size_t)row * 32 + (tid & 31)];
    float ssq2 = a0 * a0 + a1 * a1;
    float ssk2 = ak * ak;
    block_reduce_sum2_256(ssq2, ssk2, scratch);
    float r2  = rsqrtf(ssq2 / 512.f + EPS_);
    float rk2 = rsqrtf(ssk2 / 128.f + EPS_);
    sh[tid] = a0 * r2 * g_postq[tid];
    sh[tid + 256] = a1 * r2 * g_postq[tid + 256];
    if (tid < 128) sh[512 + tid] = ak * rk2 * g_postk[tid];
    __syncthreads();
    if (tid < 16) {
        float ssh = 0.f;
        for (int d = 0; d < 32; ++d) { float x = sh[tid * 32 + d]; ssh += x * x; }
        // sqrt(32)*(1/sqrt(32)) == 1: attention scale folded into q.
        // LOG2E folded too so attn softmax is a bare exp2(st + shift).
        hscale[tid] = LOG2E_ / fmaxf(sqrtf(ssh), 1e-12f);
    } else if (tid < 20) {
        int h = tid - 16;
        float ssh = 0.f;
        for (int d = 0; d < 32; ++d) { float x = sh[512 + h * 32 + d]; ssh += x * x; }
        hscale[tid] = sqrtf(32.f) / fmaxf(sqrtf(ssh), 1e-12f) * key_temp[0];
    }
    __syncthreads();
    {   // q RoPE: 256 pairs, packed 4B store
        int i0 = tid * 2;
        int h = i0 >> 5;
        int fi = (i0 & 31) >> 1;
        float sc = hscale[h];
        float x1 = sh[i0] * sc, x2 = sh[i0 + 1] * sc;
        float2 cssn = *(const float2*)&rtab[((size_t)s * 16 + fi) * 2];
        float cs = cssn.x, sn = cssn.y;
        unsigned lo = (unsigned short)f2bs(x1 * cs - x2 * sn);
        unsigned hi = (unsigned short)f2bs(x1 * sn + x2 * cs);
        *(unsigned*)(qb + (size_t)row * 512 + i0) = lo | (hi << 16);
    }
    if (tid < 64) {  // k RoPE: 64 pairs, packed 4B store
        int i0 = tid * 2;
        int h = i0 >> 5;
        int fi = (i0 & 31) >> 1;
        float sc = hscale[16 + h];
        float x1 = sh[512 + i0] * sc, x2 = sh[512 + i0 + 1] * sc;
        float2 cssn = *(const float2*)&rtab[((size_t)s * 16 + fi) * 2];
        float cs = cssn.x, sn = cssn.y;
        unsigned lo = (unsigned short)f2bs(x1 * cs - x2 * sn);
        unsigned hi = (unsigned short)f2bs(x1 * sn + x2 * cs);
        *(unsigned*)(kb + (size_t)row * 128 + i0) = lo | (hi << 16);
    }
}

// MFMA flash attention, qt-paired, in-kernel divide, bf16 O output.
// NOW T3/T4-pipelined: triple-buffered K/V LDS, 2-tile-deep prefetch, counted
// s_waitcnt vmcnt(2) + raw s_barrier per k-tile — in-flight prefetch loads are
// never drained (the old __syncthreads vmcnt(0) drain was the ~600cyc/iter stall).
// Hazard proof: each wave waits vmcnt(2) (own tile-t K+V landed, t+1 in flight)
// BEFORE the barrier, so after the barrier all 4 waves' quarters of tile t are
// in LDS; the t+2 issue after the barrier targets buffer (t-1)%3 whose readers
// all passed the barrier. Last iter waits vmcnt(0).
__global__ __launch_bounds__(256) void attn_mfma(
    const short* __restrict__ qb, const short* __restrict__ kb,
    const short* __restrict__ vtb, short* __restrict__ obf,
    const float* __restrict__ key_temp) {
    int pair = blockIdx.x, h = blockIdx.y, b = blockIdx.z;
    int kvh = h >> 2;
    __shared__ short KF[3][2048];                   // K A-frags, 3-buf 12KB
    __shared__ short VF[3][2048];                   // V B-frags, 3-buf 12KB
    __shared__ __align__(16) short PF[4 * 16 * 72]; // per-wave P, 9KB
    int tid = threadIdx.x, wave = tid >> 6, lane = tid & 63;
    int cc = lane & 15, quad = lane >> 4;
    short* PFw = PF + wave * 16 * 72;
    int ldsoff = wave * 512;
    float shift2 = -5.6568543f * key_temp[0] * LOG2E_;
    float4v zinit = {shift2, shift2, shift2, shift2};  // folded into QK^T C-operand
    short8 ones;
#pragma unroll
    for (int j = 0; j < 8; ++j) ones[j] = (short)0x3F80;  // bf16 1.0

    // per-lane staging pointers (advance by 1 k-tile per issue)
    const short* ksrc0 = kb +
        ((size_t)(b * S_LEN + wave * 16 + (tid & 15)) * 128
         + kvh * 32 + ((tid >> 4) & 3) * 8);
    const short* vsrc0 = vtb +
        ((size_t)((b * 4 + kvh) * 32 + (wave & 1) * 16 + (tid & 15)) * S_LEN
         + (tid >> 7) * 32 + ((tid >> 4) & 3) * 8);

    for (int half = 0; half < 2; ++half) {
        int qt = half ? (31 - pair) : pair;
        int s0 = qt * 64;
        short8 qfrag = *(const short8*)(qb +
            ((size_t)(b * S_LEN + s0 + wave * 16 + cc) * 512 + h * 32 + quad * 8));
        float4v accO[2];
        accO[0] = (float4v){0.f, 0.f, 0.f, 0.f};
        accO[1] = (float4v){0.f, 0.f, 0.f, 0.f};
        float4v accL = (float4v){0.f, 0.f, 0.f, 0.f};
        int qpos = s0 + wave * 16 + cc;
        const short* ksrc = ksrc0;
        const short* vsrc = vsrc0;
        int nkt = qt + 1;

        __syncthreads();   // full drain between halves (buffers recycled)
        // prologue: 2-deep prefetch
        async_copy16(ksrc, KF[0] + ldsoff);
        async_copy16(vsrc, VF[0] + ldsoff);
        ksrc += 64 * 128; vsrc += 64;
        if (nkt > 1) {
            async_copy16(ksrc, KF[1] + ldsoff);
            async_copy16(vsrc, VF[1] + ldsoff);
            ksrc += 64 * 128; vsrc += 64;
        }
        int bi = 0;
        for (int kt = 0; kt < nkt; ++kt) {
            if (kt + 1 < nkt) asm volatile("s_waitcnt vmcnt(2)" ::: "memory");
            else              asm volatile("s_waitcnt vmcnt(0)" ::: "memory");
            __builtin_amdgcn_sched_barrier(0);
            __builtin_amdgcn_s_barrier();
            __builtin_amdgcn_sched_barrier(0);
            if (kt + 2 < nkt) {
                int bn = bi ? bi - 1 : 2;   // (bi+2)%3
                async_copy16(ksrc, KF[bn] + ldsoff);
                async_copy16(vsrc, VF[bn] + ldsoff);
                ksrc += 64 * 128; vsrc += 64;
            }
            const short* KFc = KF[bi];
            const short* VFc = VF[bi];

            // S^T = K·Q^T + shift (C-init): lane holds kpos=chunk*16+quad*4+r, qcol=cc
            float4v st[4];
#pragma unroll
            for (int chunk = 0; chunk < 4; ++chunk) {
                short8 kfrag = *(const short8*)&KFc[chunk * 512 + lane * 8];
                st[chunk] = __builtin_amdgcn_mfma_f32_16x16x32_bf16(kfrag, qfrag, zinit, 0, 0, 0);
            }

            bool diag = (kt == qt);
#pragma unroll
            for (int chunk = 0; chunk < 4; ++chunk) {
                float pv[4];
#pragma unroll
                for (int r = 0; r < 4; ++r) {
                    float e = exp2f(st[chunk][r]);   // scale+shift pre-folded
                    if (diag) {
                        int kpos = kt * 64 + chunk * 16 + quad * 4 + r;
                        e = (kpos <= qpos) ? e : 0.f;
                    }
                    pv[r] = e;
                }
                unsigned u0, u1;   // packed bf16 pairs (RNE)
                asm("v_cvt_pk_bf16_f32 %0, %1, %2" : "=v"(u0) : "v"(pv[0]), "v"(pv[1]));
                asm("v_cvt_pk_bf16_f32 %0, %1, %2" : "=v"(u1) : "v"(pv[2]), "v"(pv[3]));
                *(uint2*)&PFw[cc * 72 + chunk * 16 + quad * 4] = make_uint2(u0, u1);
            }

            // PV: O[q][d] += P·V ; l[q] += P·1  (pfrag A[m=q][k], lane = q + 16*kquad)
#pragma unroll
            for (int kc = 0; kc < 2; ++kc) {
                short8 pfrag = *(const short8*)&PFw[cc * 72 + kc * 32 + quad * 8];
                accL = __builtin_amdgcn_mfma_f32_16x16x32_bf16(pfrag, ones, accL, 0, 0, 0);
#pragma unroll
                for (int dc = 0; dc < 2; ++dc) {
                    short8 vfrag = *(const short8*)&VFc[(kc * 2 + dc) * 512 + lane * 8];
                    accO[dc] = __builtin_amdgcn_mfma_f32_16x16x32_bf16(pfrag, vfrag, accO[dc], 0, 0, 0);
                }
            }
            bi = (bi == 2) ? 0 : bi + 1;
        }

        // epilogue: accL[r] = l for q=quad*4+r (same lane as accO rows); divide,
        // emit bf16. O layout: row q, d = dc*16 + cc.
#pragma unroll
        for (int r = 0; r < 4; ++r) {
            float linv = 1.f / accL[r];
            short* dst = obf +
                ((size_t)(b * S_LEN + s0 + wave * 16 + quad * 4 + r) * 512 + h * 32 + cc);
            dst[0]  = f2bs(accO[0][r] * linv);
            dst[16] = f2bs(accO[1][r] * linv);
        }
    }
}

// preout RMS on bf16 O rows, emit bf16 rows for the out GEMM
__global__ __launch_bounds__(256) void rms_preout_bf16(
    const short* __restrict__ obf, const float* __restrict__ g,
    short* __restrict__ outb) {
    int row = blockIdx.x;
    __shared__ float scratch[4];
    int tid = threadIdx.x;
    unsigned pk = *(const unsigned*)(obf + (size_t)row * 512 + tid * 2);
    float v0 = bs2f((short)(pk & 0xFFFF));
    float v1 = bs2f((short)(pk >> 16));
    float ssq = block_reduce_sum_256(v0 * v0 + v1 * v1, scratch);
    float r = rsqrtf(ssq / 512.f + EPS_);
    unsigned lo = (unsigned short)f2bs(v0 * r * g[tid * 2]);
    unsigned hi = (unsigned short)f2bs(v1 * r * g[tid * 2 + 1]);
    *(unsigned*)(outb + (size_t)row * 512 + tid * 2) = lo | (hi << 16);
}

extern "C" void kernel_launch(void* const* d_in, const int* in_sizes, int n_in,
                              void* d_out, int out_size, void* d_ws, size_t ws_size,
                              hipStream_t stream) {
    (void)in_sizes; (void)n_in; (void)out_size; (void)ws_size;
    const float* x        = (const float*)d_in[0];
    const float* w_q      = (const float*)d_in[1];
    const float* w_k      = (const float*)d_in[2];
    const float* w_v      = (const float*)d_in[3];
    const float* g_latent = (const float*)d_in[4];
    const float* g_kv     = (const float*)d_in[5];
    const float* conv_q_w = (const float*)d_in[6];
    const float* conv_k_w = (const float*)d_in[7];
    const float* g_conv   = (const float*)d_in[8];
    const float* g_kconv  = (const float*)d_in[9];
    const float* g_postq  = (const float*)d_in[10];
    const float* g_postk  = (const float*)d_in[11];
    const float* key_temp = (const float*)d_in[12];
    const float* g_preout = (const float*)d_in[13];
    const float* w_o      = (const float*)d_in[14];
    float* out = (float*)d_out;

    char* ws = (char*)d_ws;
    const size_t R = NROWS;
    float* qkv   = (float*)ws;                        ws += R * 768 * 4;
    float* qmean = (float*)ws;                        ws += R * 32 * 4;
    float* kmean = (float*)ws;                        ws += R * 32 * 4;
    float* convq = (float*)ws;                        ws += R * 512 * 4;
    float* convk = (float*)ws;                        ws += R * 128 * 4;
    short* qbb   = (short*)ws;                        ws += R * 512 * 2;
    short* kbb   = (short*)ws;                        ws += R * 128 * 2;
    short* vtb   = (short*)ws;                        ws += R * 128 * 2;
    short* xb    = (short*)ws;                        ws += R * 2048 * 2;
    short* wqkvb = (short*)ws;                        ws += 768 * 2048 * 2;
    short* w_ob  = (short*)ws;                        ws += 2048 * 512 * 2;
    float* rtab  = (float*)ws;                        ws += 2048 * 16 * 2 * 4;
    // overlays:
    float* qkv2  = convq;          // 25.2MB split-K partial: convq+convk+qbb head,
                                   // all written only AFTER rms_qkv_means consumes it
    short* obf   = xb;             // xb dead after QKV gemm: bf16 O rows
    short* attnb = xb + R * 512;   // preout-RMS'd rows for the out GEMM

    dim3 blk(256);
    cvt_all<<<16384 + 2560 + 128, blk, 0, stream>>>(x, xb, w_q, w_k, w_v, w_o,
                                                    wqkvb, w_ob, rtab);
    gemm_bf16_mfma_sk2<<<dim3(6, 64, 2), blk, 0, stream>>>(xb, wqkvb, qkv, qkv2, 768, 2048);
    rms_qkv_means<<<NROWS, blk, 0, stream>>>(qkv, qkv2, g_latent, g_kv, qmean, kmean, vtb);
    causal_conv_all<<<dim3(64, 20, 4), blk, 0, stream>>>(qkv, conv_q_w, conv_k_w,
                                                         convq, convk);
    mix_rows<<<NROWS, blk, 0, stream>>>(convq, convk, qmean, kmean, g_conv, g_kconv,
                                        g_postq, g_postk, key_temp, rtab, qbb, kbb);
    attn_mfma<<<dim3(16, 16, 4), blk, 0, stream>>>(qbb, kbb, vtb, obf, key_temp);
    rms_preout_bf16<<<NROWS, blk, 0, stream>>>(obf, g_preout, attnb);
    gemm_bf16_mfma<<<dim3(16, 64), blk, 0, stream>>>(attnb, w_ob, out, 2048, 512);
}